// Round 3
// baseline (160.162 us; speedup 1.0000x reference)
//
#include <hip/hip_runtime.h>

#define B_ 4
#define V_ 8
#define P_ 1369
#define D_ 2048
#define R_ 128
#define F_ 3
#define K_ 4
#define E_ 5476          // 4*P_
#define CAND_ 8
#define EPS_ 1e-8f

typedef unsigned short u16;
typedef __attribute__((ext_vector_type(8))) short bf16x8;
typedef __attribute__((ext_vector_type(4))) float f32x4;

__device__ inline u16 f2bf(float f){
  unsigned int u = __float_as_uint(f);
  u = u + 0x7fffu + ((u >> 16) & 1u);
  return (u16)(u >> 16);
}
__device__ inline int pack2bf(float lo, float hi){
  return (int)(((unsigned)f2bf(hi) << 16) | (unsigned)f2bf(lo));
}
__device__ inline float sq8(float4 a, float4 b){
  return a.x*a.x + a.y*a.y + a.z*a.z + a.w*a.w
       + b.x*b.x + b.y*b.y + b.z*b.z + b.w*b.w;
}
__device__ inline float huber1(float e){
  float ae = fabsf(e);
  return ae <= 1.0f ? 0.5f*e*e : (ae - 0.5f);
}
// 256-thread block sum, result returned to all threads
__device__ inline float blk_sum(float v, float* scr){
  for (int off = 32; off; off >>= 1) v += __shfl_xor(v, off, 64);
  __syncthreads();
  if ((threadIdx.x & 63) == 0) scr[threadIdx.x >> 6] = v;
  __syncthreads();
  float s = scr[0] + scr[1] + scr[2] + scr[3];
  __syncthreads();
  return s;
}

// ------------------------------------------- K0: merged prep (ref + shared rows)
__global__ __launch_bounds__(256) void k_prep(
    const float* __restrict__ teacher, const float* __restrict__ student,
    const int* __restrict__ ref_perm, const int* __restrict__ shared_perm,
    u16* __restrict__ ref_tn, float* __restrict__ rr_t, float* __restrict__ rr_s,
    u16* __restrict__ shT, u16* __restrict__ shS,
    float* __restrict__ hhT, float* __restrict__ hhS){
  __shared__ float scr[4];
  int t = threadIdx.x;
  if (blockIdx.x < 512){
    int br = blockIdx.x, b = br >> 7, r = br & 127;
    int p = ref_perm[r];
    const float* tp = teacher + ((size_t)(b*V_)*P_ + p)*D_;
    const float* sp = student + ((size_t)(b*4)*P_ + p)*D_;
    float4 x0 = *(const float4*)(tp + t*8);
    float4 x1 = *(const float4*)(tp + t*8 + 4);
    float sumt = blk_sum(sq8(x0, x1), scr);
    float4 y0 = *(const float4*)(sp + t*8);
    float4 y1 = *(const float4*)(sp + t*8 + 4);
    float sums = blk_sum(sq8(y0, y1), scr);
    if (t == 0){ rr_t[br] = sumt; rr_s[br] = sums; }
    float inv = 1.0f / fmaxf(sqrtf(sumt), 1e-12f);
    int4 pt = { pack2bf(x0.x*inv, x0.y*inv), pack2bf(x0.z*inv, x0.w*inv),
                pack2bf(x1.x*inv, x1.y*inv), pack2bf(x1.z*inv, x1.w*inv) };
    *(int4*)(ref_tn + (size_t)br*D_ + t*8) = pt;
  } else {
    int id = blockIdx.x - 512;
    int b = id / 384, fs = id % 384;
    int f = fs >> 7, s = fs & 127;
    int p = shared_perm[s];
    const float* tp = teacher + ((size_t)(b*V_ + 2 + 2*f)*P_ + p)*D_;
    const float* sp = student + ((size_t)(b*4 + 1 + f)*P_ + p)*D_;
    float4 x0 = *(const float4*)(tp + t*8);
    float4 x1 = *(const float4*)(tp + t*8 + 4);
    float sumt = blk_sum(sq8(x0, x1), scr);
    int4 pt = { pack2bf(x0.x, x0.y), pack2bf(x0.z, x0.w),
                pack2bf(x1.x, x1.y), pack2bf(x1.z, x1.w) };
    *(int4*)(shT + (size_t)id*D_ + t*8) = pt;
    float4 y0 = *(const float4*)(sp + t*8);
    float4 y1 = *(const float4*)(sp + t*8 + 4);
    float sums = blk_sum(sq8(y0, y1), scr);
    int4 ps = { pack2bf(y0.x, y0.y), pack2bf(y0.z, y0.w),
                pack2bf(y1.x, y1.y), pack2bf(y1.z, y1.w) };
    *(int4*)(shS + (size_t)id*D_ + t*8) = ps;
    if (t == 0){ hhT[id] = sumt; hhS[id] = sums; }
  }
}

// --------------- K1: sim GEMM, tile 128x32, BK=64 (bf16 MFMA, fused extra norms)
__global__ __launch_bounds__(256) void k_sim(
    const float* __restrict__ teacher, const u16* __restrict__ ref_tn,
    float* __restrict__ sim){
  __shared__ __align__(16) u16 As[128][72];
  __shared__ __align__(16) u16 Bs[32][72];
  __shared__ float nsq[32];
  int b = blockIdx.y;
  int e0 = blockIdx.x * 32;
  int t = threadIdx.x, lane = t & 63, w = t >> 6;   // wave w owns rows w*32..w*32+31
  f32x4 acc[2][2];
  for (int i = 0; i < 2; i++)
    for (int j = 0; j < 2; j++)
      acc[i][j] = (f32x4){0.f, 0.f, 0.f, 0.f};
  int arow = t >> 1, acol = (t & 1) * 32;
  int brow = t >> 3, bcol = (t & 7) * 8;
  int e = e0 + brow;
  const u16* asrc = ref_tn + ((size_t)(b*128 + arow))*D_ + acol;
  const float* bsrc = nullptr;
  if (e < E_) bsrc = teacher + ((size_t)(b*V_ + 1 + 2*(e / P_))*P_ + (e % P_))*D_ + bcol;
  float q = 0.0f;
  int lr = lane & 15;
  for (int k0 = 0; k0 < D_; k0 += 64){
    __syncthreads();
#pragma unroll
    for (int u = 0; u < 4; u++)
      *(int4*)&As[arow][acol + u*8] = *(const int4*)(asrc + k0 + u*8);
    float4 z0, z1;
    if (bsrc){ z0 = *(const float4*)(bsrc + k0); z1 = *(const float4*)(bsrc + k0 + 4); }
    else { z0 = make_float4(0.f,0.f,0.f,0.f); z1 = z0; }
    q += sq8(z0, z1);
    int4 p0 = { pack2bf(z0.x, z0.y), pack2bf(z0.z, z0.w),
                pack2bf(z1.x, z1.y), pack2bf(z1.z, z1.w) };
    *(int4*)&Bs[brow][bcol] = p0;
    __syncthreads();
#pragma unroll
    for (int kk = 0; kk < 2; kk++){
      int kof = kk*32 + (lane >> 4) * 8;
      bf16x8 bf0 = *(const bf16x8*)&Bs[lr][kof];
      bf16x8 bf1 = *(const bf16x8*)&Bs[16 + lr][kof];
#pragma unroll
      for (int mi = 0; mi < 2; mi++){
        bf16x8 af = *(const bf16x8*)&As[w*32 + mi*16 + lr][kof];
        acc[mi][0] = __builtin_amdgcn_mfma_f32_16x16x32_bf16(af, bf0, acc[mi][0], 0, 0, 0);
        acc[mi][1] = __builtin_amdgcn_mfma_f32_16x16x32_bf16(af, bf1, acc[mi][1], 0, 0, 0);
      }
    }
  }
  // row-norm partials live in 8-lane groups (one row each): reduce within group
  q += __shfl_xor(q, 1, 64);
  q += __shfl_xor(q, 2, 64);
  q += __shfl_xor(q, 4, 64);
  if ((t & 7) == 0) nsq[t >> 3] = q;
  __syncthreads();
  int lg = lane >> 4;
#pragma unroll
  for (int mi = 0; mi < 2; mi++){
#pragma unroll
    for (int ni = 0; ni < 2; ni++){
      int el = ni*16 + lr;
      int e_idx = e0 + el;
      if (e_idx < E_){
        float inv = 1.0f / fmaxf(sqrtf(nsq[el]), 1e-12f);
#pragma unroll
        for (int reg = 0; reg < 4; reg++){
          int r_idx = w*32 + mi*16 + lg*4 + reg;
          sim[((size_t)(b*128 + r_idx))*E_ + e_idx] = acc[mi][ni][reg] * inv;
        }
      }
    }
  }
}

// ---- K2: fused top-8 select + fp32 rescore + exact top-4 + pack B-operands
__global__ __launch_bounds__(256) void k_rescore(
    const float* __restrict__ teacher, const float* __restrict__ student,
    const int* __restrict__ ref_perm, const float* __restrict__ sim,
    const float* __restrict__ rr_t,
    u16* __restrict__ packT, u16* __restrict__ packS,
    float* __restrict__ kkw, float* __restrict__ rkT, float* __restrict__ rkS){
  __shared__ float v[E_];
  __shared__ float rT[D_];
  __shared__ float rS[D_];
  __shared__ float tv[256];
  __shared__ int   ti[256];
  __shared__ float rv[4];
  __shared__ int ri[4];
  __shared__ int cand[CAND_];
  __shared__ float csim[CAND_], cq[CAND_], cdT[CAND_];
  __shared__ int order[4];
  int br = blockIdx.x, b = br >> 7, r = br & 127, t = threadIdx.x;
  int lane = t & 63, w = t >> 6;
  // ---- phase A: top-8 of this row of sim (cached per-thread maxima)
  const float* row = sim + (size_t)br*E_;
  for (int i = t; i < E_; i += 256) v[i] = row[i];
  __syncthreads();
  {
    float bv = -3.4e38f; int bi = 0x7fffffff;
    for (int i = t; i < E_; i += 256){
      float x = v[i];
      if (x > bv){ bv = x; bi = i; }
    }
    tv[t] = bv; ti[t] = bi;
  }
  __syncthreads();
  for (int c = 0; c < CAND_; c++){
    float mv = tv[t]; int mi2 = ti[t];
    for (int off = 32; off; off >>= 1){
      float ov = __shfl_down(mv, off, 64);
      int   oi = __shfl_down(mi2, off, 64);
      if (ov > mv || (ov == mv && oi < mi2)){ mv = ov; mi2 = oi; }
    }
    if (lane == 0){ rv[w] = mv; ri[w] = mi2; }
    __syncthreads();
    if (t == 0){
      for (int w2 = 1; w2 < 4; w2++)
        if (rv[w2] > rv[0] || (rv[w2] == rv[0] && ri[w2] < ri[0])){ rv[0] = rv[w2]; ri[0] = ri[w2]; }
      cand[c] = ri[0];
      v[ri[0]] = -3.4e38f;
    }
    __syncthreads();
    int win = cand[c];
    if (t == (win & 255)){           // owner (stride-256 scan) recomputes its max
      float nb = -3.4e38f; int nbi = 0x7fffffff;
      for (int i = t; i < E_; i += 256){
        float x = v[i];
        if (x > nb){ nb = x; nbi = i; }
      }
      tv[t] = nb; ti[t] = nbi;
    }
    __syncthreads();
  }
  // ---- phase B: ref rows to LDS + pack j=4
  int p = ref_perm[r];
  const float* tp = teacher + ((size_t)(b*V_)*P_ + p)*D_;
  const float* sp = student + ((size_t)(b*4)*P_ + p)*D_;
  float4 x0 = *(const float4*)(tp + t*8);
  float4 x1 = *(const float4*)(tp + t*8 + 4);
  float4 y0 = *(const float4*)(sp + t*8);
  float4 y1 = *(const float4*)(sp + t*8 + 4);
  *(float4*)&rT[t*8]   = x0; *(float4*)&rT[t*8+4] = x1;
  *(float4*)&rS[t*8]   = y0; *(float4*)&rS[t*8+4] = y1;
  {
    int4 pt = { pack2bf(x0.x, x0.y), pack2bf(x0.z, x0.w),
                pack2bf(x1.x, x1.y), pack2bf(x1.z, x1.w) };
    *(int4*)(packT + ((size_t)(br*5 + 4))*D_ + t*8) = pt;
    int4 ps = { pack2bf(y0.x, y0.y), pack2bf(y0.z, y0.w),
                pack2bf(y1.x, y1.y), pack2bf(y1.z, y1.w) };
    *(int4*)(packS + ((size_t)(br*5 + 4))*D_ + t*8) = ps;
  }
  float invt = 1.0f / fmaxf(sqrtf(rr_t[br]), 1e-12f);
  __syncthreads();
  // ---- phase C: wave-parallel candidate scoring (dot with rT, norm^2)
  for (int c = w; c < CAND_; c += 4){
    int e = cand[c];
    const float* xp = teacher + ((size_t)(b*V_ + 1 + 2*(e / P_))*P_ + (e % P_))*D_;
    float d = 0.f, q = 0.f;
#pragma unroll
    for (int j = 0; j < 32; j++){
      float xv = xp[lane + 64*j];
      d += xv * rT[lane + 64*j];
      q += xv * xv;
    }
    for (int off = 32; off; off >>= 1){
      d += __shfl_xor(d, off, 64);
      q += __shfl_xor(q, off, 64);
    }
    if (lane == 0){
      cdT[c] = d; cq[c] = q;
      csim[c] = d * invt / fmaxf(sqrtf(q), 1e-12f);
    }
  }
  __syncthreads();
  // ---- phase D: exact top-4 ordering among the 8 candidates
  if (t == 0){
    unsigned used = 0;
    for (int k = 0; k < 4; k++){
      int best = -1;
      for (int c = 0; c < CAND_; c++){
        if (used & (1u << c)) continue;
        if (best < 0){ best = c; continue; }
        if (csim[c] > csim[best] ||
            (csim[c] == csim[best] && cand[c] < cand[best])) best = c;
      }
      used |= 1u << best;
      order[k] = best;
    }
  }
  __syncthreads();
  // ---- phase E: wave w handles winner k=w: rkS dot + pack
  {
    int c = order[w];
    int e = cand[c];
    const float* xp = teacher + ((size_t)(b*V_ + 1 + 2*(e / P_))*P_ + (e % P_))*D_;
    float ds = 0.f;
#pragma unroll
    for (int j = 0; j < 32; j++)
      ds += xp[lane + 64*j] * rS[lane + 64*j];
    for (int off = 32; off; off >>= 1) ds += __shfl_xor(ds, off, 64);
    if (lane == 0){
      kkw[br*4 + w] = cq[c];
      rkT[br*4 + w] = cdT[c];
      rkS[br*4 + w] = ds;
    }
    const float* src = xp + lane*32;
#pragma unroll
    for (int u = 0; u < 4; u++){
      float4 a  = *(const float4*)(src + u*8);
      float4 b2 = *(const float4*)(src + u*8 + 4);
      int4 pc = { pack2bf(a.x, a.y), pack2bf(a.z, a.w),
                  pack2bf(b2.x, b2.y), pack2bf(b2.z, b2.w) };
      size_t po = ((size_t)(br*5 + w))*D_ + lane*32 + u*8;
      *(int4*)(packT + po) = pc;
      *(int4*)(packS + po) = pc;
    }
  }
}

// -------------- K3: angle GEMM, tile 64x64, BK=64  out[b][fs][r*5+j] = h . pack
__global__ __launch_bounds__(256) void k_angle_gemm(
    const u16* __restrict__ shT, const u16* __restrict__ shS,
    const u16* __restrict__ packT, const u16* __restrict__ packS,
    float* __restrict__ outT, float* __restrict__ outS){
  __shared__ __align__(16) u16 As[64][72];
  __shared__ __align__(16) u16 Bs[64][72];
  int which = blockIdx.z;
  const u16* A  = which ? shS : shT;
  const u16* Bp = which ? packS : packT;
  float* out = which ? outS : outT;
  int b = blockIdx.y;
  int mt = blockIdx.x % 6, nt = blockIdx.x / 6;
  int m0 = mt*64, n0 = nt*64;
  int t = threadIdx.x, lane = t & 63, w = t >> 6, wm = w >> 1, wn = w & 1;
  f32x4 acc[2][2];
  for (int i = 0; i < 2; i++)
    for (int j = 0; j < 2; j++)
      acc[i][j] = (f32x4){0.f, 0.f, 0.f, 0.f};
  int arow = t >> 2, acol = (t & 3) * 16;
  const u16* asrc = A  + ((size_t)(b*384 + m0 + arow))*D_ + acol;
  const u16* bsrc = Bp + ((size_t)(b*640 + n0 + arow))*D_ + acol;
  int lr = lane & 15;
  for (int k0 = 0; k0 < D_; k0 += 64){
    __syncthreads();
    *(int4*)&As[arow][acol]     = *(const int4*)(asrc + k0);
    *(int4*)&As[arow][acol + 8] = *(const int4*)(asrc + k0 + 8);
    *(int4*)&Bs[arow][acol]     = *(const int4*)(bsrc + k0);
    *(int4*)&Bs[arow][acol + 8] = *(const int4*)(bsrc + k0 + 8);
    __syncthreads();
#pragma unroll
    for (int kk = 0; kk < 2; kk++){
      int kof = kk*32 + (lane >> 4) * 8;
      bf16x8 bf0 = *(const bf16x8*)&Bs[wn*32 + lr][kof];
      bf16x8 bf1 = *(const bf16x8*)&Bs[wn*32 + 16 + lr][kof];
#pragma unroll
      for (int mi = 0; mi < 2; mi++){
        bf16x8 af = *(const bf16x8*)&As[wm*32 + mi*16 + lr][kof];
        acc[mi][0] = __builtin_amdgcn_mfma_f32_16x16x32_bf16(af, bf0, acc[mi][0], 0, 0, 0);
        acc[mi][1] = __builtin_amdgcn_mfma_f32_16x16x32_bf16(af, bf1, acc[mi][1], 0, 0, 0);
      }
    }
  }
  int lg = lane >> 4;
#pragma unroll
  for (int mi = 0; mi < 2; mi++)
#pragma unroll
    for (int ni = 0; ni < 2; ni++)
#pragma unroll
      for (int reg = 0; reg < 4; reg++){
        int r_idx = wm*32 + mi*16 + lg*4 + reg;
        int c_idx = wn*32 + ni*16 + lr;
        out[((size_t)(b*384 + m0 + r_idx))*640 + n0 + c_idx] = acc[mi][ni][reg];
      }
}

// ---------- K4: assemble angles + huber + partials (coalesced: r fastest)
__global__ __launch_bounds__(256) void k_assemble(
    const float* __restrict__ outT, const float* __restrict__ outS,
    const float* __restrict__ hhT, const float* __restrict__ hhS,
    const float* __restrict__ rrT, const float* __restrict__ rrS,
    const float* __restrict__ kkw, const float* __restrict__ rkT, const float* __restrict__ rkS,
    double* __restrict__ partials){
  __shared__ double dscr[4];
  int idx = blockIdx.x*256 + threadIdx.x;         // [0, 196608)
  int r = idx & 127, s = (idx >> 7) & 127, bf = idx >> 14;
  int f = bf % 3, b = bf / 3;
  int fs = f*128 + s;
  const float* oT = outT + ((size_t)(b*384 + fs))*640 + r*5;
  const float* oS = outS + ((size_t)(b*384 + fs))*640 + r*5;
  float hh_t = hhT[b*384 + fs], hh_s = hhS[b*384 + fs];
  float rr_tv = rrT[b*128 + r], rr_sv = rrS[b*128 + r];
  float sr_t = oT[4], sr_s = oS[4];
  float nhr_t = sqrtf(fmaxf(hh_t + rr_tv - 2.0f*sr_t, 0.0f));
  float nhr_s = sqrtf(fmaxf(hh_s + rr_sv - 2.0f*sr_s, 0.0f));
  float h1 = 0.f, h2 = 0.f, h3 = 0.f;
#pragma unroll
  for (int k = 0; k < 4; k++){
    float ss_t = oT[k], ss_s = oS[k];
    float kk = kkw[(b*128 + r)*4 + k];
    float rk_t = rkT[(b*128 + r)*4 + k];
    float rk_s = rkS[(b*128 + r)*4 + k];
    float ncr_t = sqrtf(fmaxf(kk + rr_tv - 2.0f*rk_t, 0.0f));
    float ncr_s = sqrtf(fmaxf(kk + rr_sv - 2.0f*rk_s, 0.0f));
    float nhc_t = sqrtf(fmaxf(hh_t + kk - 2.0f*ss_t, 0.0f));
    float nhc_s = sqrtf(fmaxf(hh_s + kk - 2.0f*ss_s, 0.0f));
    float a1t = (ss_t - sr_t - rk_t + rr_tv) / (fmaxf(nhr_t, EPS_) * fmaxf(ncr_t, EPS_));
    float a2t = (sr_t - rk_t - ss_t + kk)    / (fmaxf(ncr_t, EPS_) * fmaxf(nhc_t, EPS_));
    float a3t = (rk_t - sr_t - ss_t + hh_t)  / (fmaxf(nhr_t, EPS_) * fmaxf(nhc_t, EPS_));
    float a1s = (ss_s - sr_s - rk_s + rr_sv) / (fmaxf(nhr_s, EPS_) * fmaxf(ncr_s, EPS_));
    float a2s = (sr_s - rk_s - ss_s + kk)    / (fmaxf(ncr_s, EPS_) * fmaxf(nhc_s, EPS_));
    float a3s = (rk_s - sr_s - ss_s + hh_s)  / (fmaxf(nhr_s, EPS_) * fmaxf(nhc_s, EPS_));
    h1 += huber1(a1s - a1t);
    h2 += huber1(a2s - a2t);
    h3 += huber1(a3s - a3t);
  }
  double d1 = h1, d2 = h2, d3 = h3;
  for (int off = 32; off; off >>= 1){
    d1 += __shfl_xor(d1, off, 64);
    d2 += __shfl_xor(d2, off, 64);
    d3 += __shfl_xor(d3, off, 64);
  }
  int w = threadIdx.x >> 6;
  if ((threadIdx.x & 63) == 0) dscr[w] = d1;
  __syncthreads();
  if (threadIdx.x == 0) partials[blockIdx.x*3 + 0] = dscr[0]+dscr[1]+dscr[2]+dscr[3];
  __syncthreads();
  if ((threadIdx.x & 63) == 0) dscr[w] = d2;
  __syncthreads();
  if (threadIdx.x == 0) partials[blockIdx.x*3 + 1] = dscr[0]+dscr[1]+dscr[2]+dscr[3];
  __syncthreads();
  if ((threadIdx.x & 63) == 0) dscr[w] = d3;
  __syncthreads();
  if (threadIdx.x == 0) partials[blockIdx.x*3 + 2] = dscr[0]+dscr[1]+dscr[2]+dscr[3];
}

// ------------------------------------------------------------- K5: final reduce
__global__ __launch_bounds__(256) void k_final(
    const double* __restrict__ partials, float* __restrict__ out){
  __shared__ double dscr[12];
  int t = threadIdx.x;
  double l1 = 0, l2 = 0, l3 = 0;
  for (int i = t; i < 768; i += 256){
    l1 += partials[i*3 + 0];
    l2 += partials[i*3 + 1];
    l3 += partials[i*3 + 2];
  }
  for (int off = 32; off; off >>= 1){
    l1 += __shfl_xor(l1, off, 64);
    l2 += __shfl_xor(l2, off, 64);
    l3 += __shfl_xor(l3, off, 64);
  }
  int w = t >> 6;
  if ((t & 63) == 0){ dscr[w*3] = l1; dscr[w*3+1] = l2; dscr[w*3+2] = l3; }
  __syncthreads();
  if (t == 0){
    double L1 = dscr[0] + dscr[3] + dscr[6] + dscr[9];
    double L2 = dscr[1] + dscr[4] + dscr[7] + dscr[10];
    double L3 = dscr[2] + dscr[5] + dscr[8] + dscr[11];
    out[0] = (float)((L1 + L2 + L3) / 786432.0);
  }
}

extern "C" void kernel_launch(void* const* d_in, const int* in_sizes, int n_in,
                              void* d_out, int out_size, void* d_ws, size_t ws_size,
                              hipStream_t stream){
  (void)in_sizes; (void)n_in; (void)out_size; (void)ws_size;
  const float* teacher = (const float*)d_in[0];
  const float* student = (const float*)d_in[1];
  const int* ref_perm = (const int*)d_in[2];
  const int* shared_perm = (const int*)d_in[3];
  float* out = (float*)d_out;

  char* ws = (char*)d_ws;
  size_t off = 0;
  auto alloc = [&](size_t bytes)->char*{
    char* pp = ws + off;
    off += (bytes + 255) & ~(size_t)255;
    return pp;
  };
  u16*    ref_tn  = (u16*)   alloc((size_t)B_*R_*D_*sizeof(u16));      // 2 MB
  float*  rr_t    = (float*) alloc(B_*R_*sizeof(float));
  float*  rr_s    = (float*) alloc(B_*R_*sizeof(float));
  float*  kkw     = (float*) alloc(B_*R_*K_*sizeof(float));
  float*  rkT     = (float*) alloc(B_*R_*K_*sizeof(float));
  float*  rkS     = (float*) alloc(B_*R_*K_*sizeof(float));
  u16*    shT     = (u16*)   alloc((size_t)B_*384*D_*sizeof(u16));     // 6.3 MB
  u16*    shS     = (u16*)   alloc((size_t)B_*384*D_*sizeof(u16));     // 6.3 MB
  float*  hhT     = (float*) alloc(B_*384*sizeof(float));
  float*  hhS     = (float*) alloc(B_*384*sizeof(float));
  float*  outT    = (float*) alloc((size_t)B_*384*640*sizeof(float));  // 3.9 MB
  float*  outS    = (float*) alloc((size_t)B_*384*640*sizeof(float));  // 3.9 MB
  double* partials= (double*)alloc(768*3*sizeof(double));
  float*  sim     = (float*) alloc((size_t)B_*R_*E_*sizeof(float));    // 11.2 MB
  u16*    packT   = (u16*)   alloc((size_t)B_*R_*5*D_*sizeof(u16));    // 10.5 MB
  u16*    packS   = (u16*)   alloc((size_t)B_*R_*5*D_*sizeof(u16));    // 10.5 MB

  k_prep<<<dim3(2048), dim3(256), 0, stream>>>(teacher, student, ref_perm, shared_perm,
                                               ref_tn, rr_t, rr_s, shT, shS, hhT, hhS);
  k_sim<<<dim3((E_ + 31)/32, B_), dim3(256), 0, stream>>>(teacher, ref_tn, sim);
  k_rescore<<<dim3(B_*R_), dim3(256), 0, stream>>>(teacher, student, ref_perm, sim, rr_t,
                                                   packT, packS, kkw, rkT, rkS);
  k_angle_gemm<<<dim3(60, B_, 2), dim3(256), 0, stream>>>(shT, shS, packT, packS, outT, outS);
  k_assemble<<<dim3(768), dim3(256), 0, stream>>>(outT, outS, hhT, hhS, rr_t, rr_s, kkw, rkT, rkS, partials);
  k_final<<<dim3(1), dim3(256), 0, stream>>>(partials, out);
}

// Round 4
// 133.807 us; speedup vs baseline: 1.1970x; 1.1970x over previous
//
#include <hip/hip_runtime.h>

#define B_ 4
#define V_ 8
#define P_ 1369
#define D_ 2048
#define R_ 128
#define F_ 3
#define K_ 4
#define E_ 5476          // 4*P_
#define CAND_ 8
#define EPS_ 1e-8f
#define ETILES_ 86       // ceil(E_/64)
#define SIMBLK_ (ETILES_*B_*2)   // 688 split-K sim blocks

typedef unsigned short u16;
typedef __attribute__((ext_vector_type(8))) short bf16x8;
typedef __attribute__((ext_vector_type(4))) float f32x4;

__device__ inline u16 f2bf(float f){
  unsigned int u = __float_as_uint(f);
  u = u + 0x7fffu + ((u >> 16) & 1u);
  return (u16)(u >> 16);
}
__device__ inline int pack2bf(float lo, float hi){
  return (int)(((unsigned)f2bf(hi) << 16) | (unsigned)f2bf(lo));
}
__device__ inline float sq8(float4 a, float4 b){
  return a.x*a.x + a.y*a.y + a.z*a.z + a.w*a.w
       + b.x*b.x + b.y*b.y + b.z*b.z + b.w*b.w;
}
__device__ inline float huber1(float e){
  float ae = fabsf(e);
  return ae <= 1.0f ? 0.5f*e*e : (ae - 0.5f);
}
__device__ inline float blk_sum(float v, float* scr){
  for (int off = 32; off; off >>= 1) v += __shfl_xor(v, off, 64);
  __syncthreads();
  if ((threadIdx.x & 63) == 0) scr[threadIdx.x >> 6] = v;
  __syncthreads();
  float s = scr[0] + scr[1] + scr[2] + scr[3];
  __syncthreads();
  return s;
}

// -------------------------------------------------- K0: ref-row prep (512 blocks)
__global__ __launch_bounds__(256) void k_prep_ref(
    const float* __restrict__ teacher, const float* __restrict__ student,
    const int* __restrict__ ref_perm,
    u16* __restrict__ ref_tn, float* __restrict__ rr_t, float* __restrict__ rr_s){
  __shared__ float scr[4];
  int br = blockIdx.x, b = br >> 7, r = br & 127, t = threadIdx.x;
  int p = ref_perm[r];
  const float* tp = teacher + ((size_t)(b*V_)*P_ + p)*D_;
  const float* sp = student + ((size_t)(b*4)*P_ + p)*D_;
  float4 x0 = *(const float4*)(tp + t*8);
  float4 x1 = *(const float4*)(tp + t*8 + 4);
  float sumt = blk_sum(sq8(x0, x1), scr);
  float4 y0 = *(const float4*)(sp + t*8);
  float4 y1 = *(const float4*)(sp + t*8 + 4);
  float sums = blk_sum(sq8(y0, y1), scr);
  if (t == 0){ rr_t[br] = sumt; rr_s[br] = sums; }
  float inv = 1.0f / fmaxf(sqrtf(sumt), 1e-12f);
  int4 pt = { pack2bf(x0.x*inv, x0.y*inv), pack2bf(x0.z*inv, x0.w*inv),
              pack2bf(x1.x*inv, x1.y*inv), pack2bf(x1.z*inv, x1.w*inv) };
  *(int4*)(ref_tn + (size_t)br*D_ + t*8) = pt;
}

// ---- K1: FUSED dispatch: [0,688) split-K sim GEMM blocks; [688,2224) shared-prep
// sim: tile 128x64, BK=64, K-half per block; writes fp32 partial C + partial norms
__global__ __launch_bounds__(256) void k_sim_fused(
    const float* __restrict__ teacher, const float* __restrict__ student,
    const u16* __restrict__ ref_tn, const int* __restrict__ shared_perm,
    float* __restrict__ simPart, float* __restrict__ nsqPart,
    u16* __restrict__ shT, u16* __restrict__ shS,
    float* __restrict__ hhT, float* __restrict__ hhS){
  __shared__ __align__(16) u16 As[128][72];
  __shared__ __align__(16) u16 Bs[64][72];
  __shared__ float scr4[4];
  int bx = blockIdx.x, t = threadIdx.x;
  if (bx < SIMBLK_){
    int h = bx / (ETILES_*B_);
    int rem = bx % (ETILES_*B_);
    int b = rem / ETILES_, et = rem % ETILES_;
    int e0 = et * 64;
    int lane = t & 63, w = t >> 6, wm = w >> 1, wn = w & 1;
    f32x4 acc[4][2];
    for (int i = 0; i < 4; i++)
      for (int j = 0; j < 2; j++)
        acc[i][j] = (f32x4){0.f, 0.f, 0.f, 0.f};
    int arow = t >> 1, acol = (t & 1) * 32;
    int brow = t >> 2, bcol = (t & 3) * 16;
    int e = e0 + brow;
    const u16* asrc = ref_tn + ((size_t)(b*128 + arow))*D_ + acol;
    const float* bsrc = nullptr;
    if (e < E_) bsrc = teacher + ((size_t)(b*V_ + 1 + 2*(e / P_))*P_ + (e % P_))*D_ + bcol;
    float q = 0.0f;
    int lr = lane & 15;
    int kbeg = h * 1024, kend = kbeg + 1024;
    for (int k0 = kbeg; k0 < kend; k0 += 64){
      __syncthreads();
#pragma unroll
      for (int u = 0; u < 4; u++)
        *(int4*)&As[arow][acol + u*8] = *(const int4*)(asrc + k0 + u*8);
      float4 z0, z1, z2, z3;
      if (bsrc){
        z0 = *(const float4*)(bsrc + k0);      z1 = *(const float4*)(bsrc + k0 + 4);
        z2 = *(const float4*)(bsrc + k0 + 8);  z3 = *(const float4*)(bsrc + k0 + 12);
      } else {
        z0 = make_float4(0.f,0.f,0.f,0.f); z1 = z0; z2 = z0; z3 = z0;
      }
      q += sq8(z0, z1) + sq8(z2, z3);
      int4 p0 = { pack2bf(z0.x, z0.y), pack2bf(z0.z, z0.w),
                  pack2bf(z1.x, z1.y), pack2bf(z1.z, z1.w) };
      int4 p1 = { pack2bf(z2.x, z2.y), pack2bf(z2.z, z2.w),
                  pack2bf(z3.x, z3.y), pack2bf(z3.z, z3.w) };
      *(int4*)&Bs[brow][bcol]     = p0;
      *(int4*)&Bs[brow][bcol + 8] = p1;
      __syncthreads();
#pragma unroll
      for (int kk = 0; kk < 2; kk++){
        int kof = kk*32 + (lane >> 4) * 8;
        bf16x8 bf0 = *(const bf16x8*)&Bs[wn*32 + lr][kof];
        bf16x8 bf1 = *(const bf16x8*)&Bs[wn*32 + 16 + lr][kof];
#pragma unroll
        for (int mi = 0; mi < 4; mi++){
          bf16x8 af = *(const bf16x8*)&As[wm*64 + mi*16 + lr][kof];
          acc[mi][0] = __builtin_amdgcn_mfma_f32_16x16x32_bf16(af, bf0, acc[mi][0], 0, 0, 0);
          acc[mi][1] = __builtin_amdgcn_mfma_f32_16x16x32_bf16(af, bf1, acc[mi][1], 0, 0, 0);
        }
      }
    }
    // partial row-norms: 4 threads per e-row
    q += __shfl_xor(q, 1, 64);
    q += __shfl_xor(q, 2, 64);
    if ((t & 3) == 0 && e < E_) nsqPart[(size_t)(h*4 + b)*E_ + e] = q;
    int lg = lane >> 4;
#pragma unroll
    for (int mi = 0; mi < 4; mi++){
#pragma unroll
      for (int ni = 0; ni < 2; ni++){
        int el = wn*32 + ni*16 + lr;
        int e_idx = e0 + el;
        if (e_idx < E_){
#pragma unroll
          for (int reg = 0; reg < 4; reg++){
            int r_idx = wm*64 + mi*16 + lg*4 + reg;
            simPart[((size_t)((h*4 + b)*128 + r_idx))*E_ + e_idx] = acc[mi][ni][reg];
          }
        }
      }
    }
  } else {
    // ---------------- shared-row prep (1536 blocks)
    int id = bx - SIMBLK_;
    int b = id / 384, fs = id % 384;
    int f = fs >> 7, s = fs & 127;
    int p = shared_perm[s];
    const float* tp = teacher + ((size_t)(b*V_ + 2 + 2*f)*P_ + p)*D_;
    const float* sp = student + ((size_t)(b*4 + 1 + f)*P_ + p)*D_;
    float4 x0 = *(const float4*)(tp + t*8);
    float4 x1 = *(const float4*)(tp + t*8 + 4);
    float sumt = blk_sum(sq8(x0, x1), scr4);
    int4 pt = { pack2bf(x0.x, x0.y), pack2bf(x0.z, x0.w),
                pack2bf(x1.x, x1.y), pack2bf(x1.z, x1.w) };
    *(int4*)(shT + (size_t)id*D_ + t*8) = pt;
    float4 y0 = *(const float4*)(sp + t*8);
    float4 y1 = *(const float4*)(sp + t*8 + 4);
    float sums = blk_sum(sq8(y0, y1), scr4);
    int4 ps = { pack2bf(y0.x, y0.y), pack2bf(y0.z, y0.w),
                pack2bf(y1.x, y1.y), pack2bf(y1.z, y1.w) };
    *(int4*)(shS + (size_t)id*D_ + t*8) = ps;
    if (t == 0){ hhT[id] = sumt; hhS[id] = sums; }
  }
}

// ---- K2: combine partials + top-8 select + fp32 rescore + exact top-4 + pack
__global__ __launch_bounds__(256) void k_rescore(
    const float* __restrict__ teacher, const float* __restrict__ student,
    const int* __restrict__ ref_perm,
    const float* __restrict__ simPart, const float* __restrict__ nsqPart,
    const float* __restrict__ rr_t,
    u16* __restrict__ packT, u16* __restrict__ packS,
    float* __restrict__ kkw, float* __restrict__ rkT, float* __restrict__ rkS){
  __shared__ float v[E_];
  __shared__ float rT[D_];
  __shared__ float rS[D_];
  __shared__ float tv[256];
  __shared__ int   ti[256];
  __shared__ float rv[4];
  __shared__ int ri[4];
  __shared__ int cand[CAND_];
  __shared__ float csim[CAND_], cq[CAND_], cdT[CAND_];
  __shared__ int order[4];
  int br = blockIdx.x, b = br >> 7, r = br & 127, t = threadIdx.x;
  int lane = t & 63, w = t >> 6;
  // ---- phase A: combine split-K partials -> normalized sim row; top-8
  const float* p0 = simPart + ((size_t)(b*128 + r))*E_;
  const float* p1 = simPart + ((size_t)((4 + b)*128 + r))*E_;
  const float* q0 = nsqPart + (size_t)b*E_;
  const float* q1 = nsqPart + (size_t)(4 + b)*E_;
  for (int i = t; i < E_; i += 256){
    float qq = q0[i] + q1[i];
    float inv = 1.0f / fmaxf(sqrtf(qq), 1e-12f);
    v[i] = (p0[i] + p1[i]) * inv;
  }
  __syncthreads();
  {
    float bv = -3.4e38f; int bi = 0x7fffffff;
    for (int i = t; i < E_; i += 256){
      float x = v[i];
      if (x > bv){ bv = x; bi = i; }
    }
    tv[t] = bv; ti[t] = bi;
  }
  __syncthreads();
  for (int c = 0; c < CAND_; c++){
    float mv = tv[t]; int mi2 = ti[t];
    for (int off = 32; off; off >>= 1){
      float ov = __shfl_down(mv, off, 64);
      int   oi = __shfl_down(mi2, off, 64);
      if (ov > mv || (ov == mv && oi < mi2)){ mv = ov; mi2 = oi; }
    }
    if (lane == 0){ rv[w] = mv; ri[w] = mi2; }
    __syncthreads();
    if (t == 0){
      for (int w2 = 1; w2 < 4; w2++)
        if (rv[w2] > rv[0] || (rv[w2] == rv[0] && ri[w2] < ri[0])){ rv[0] = rv[w2]; ri[0] = ri[w2]; }
      cand[c] = ri[0];
      v[ri[0]] = -3.4e38f;
    }
    __syncthreads();
    int win = cand[c];
    if (t == (win & 255)){
      float nb = -3.4e38f; int nbi = 0x7fffffff;
      for (int i = t; i < E_; i += 256){
        float x = v[i];
        if (x > nb){ nb = x; nbi = i; }
      }
      tv[t] = nb; ti[t] = nbi;
    }
    __syncthreads();
  }
  // ---- phase B: ref rows to LDS + pack j=4
  int p = ref_perm[r];
  const float* tp = teacher + ((size_t)(b*V_)*P_ + p)*D_;
  const float* sp = student + ((size_t)(b*4)*P_ + p)*D_;
  float4 x0 = *(const float4*)(tp + t*8);
  float4 x1 = *(const float4*)(tp + t*8 + 4);
  float4 y0 = *(const float4*)(sp + t*8);
  float4 y1 = *(const float4*)(sp + t*8 + 4);
  *(float4*)&rT[t*8]   = x0; *(float4*)&rT[t*8+4] = x1;
  *(float4*)&rS[t*8]   = y0; *(float4*)&rS[t*8+4] = y1;
  {
    int4 pt = { pack2bf(x0.x, x0.y), pack2bf(x0.z, x0.w),
                pack2bf(x1.x, x1.y), pack2bf(x1.z, x1.w) };
    *(int4*)(packT + ((size_t)(br*5 + 4))*D_ + t*8) = pt;
    int4 ps = { pack2bf(y0.x, y0.y), pack2bf(y0.z, y0.w),
                pack2bf(y1.x, y1.y), pack2bf(y1.z, y1.w) };
    *(int4*)(packS + ((size_t)(br*5 + 4))*D_ + t*8) = ps;
  }
  float invt = 1.0f / fmaxf(sqrtf(rr_t[br]), 1e-12f);
  __syncthreads();
  // ---- phase C: wave-parallel candidate scoring
  for (int c = w; c < CAND_; c += 4){
    int e = cand[c];
    const float* xp = teacher + ((size_t)(b*V_ + 1 + 2*(e / P_))*P_ + (e % P_))*D_;
    float d = 0.f, q = 0.f;
#pragma unroll
    for (int j = 0; j < 32; j++){
      float xv = xp[lane + 64*j];
      d += xv * rT[lane + 64*j];
      q += xv * xv;
    }
    for (int off = 32; off; off >>= 1){
      d += __shfl_xor(d, off, 64);
      q += __shfl_xor(q, off, 64);
    }
    if (lane == 0){
      cdT[c] = d; cq[c] = q;
      csim[c] = d * invt / fmaxf(sqrtf(q), 1e-12f);
    }
  }
  __syncthreads();
  // ---- phase D: exact top-4 among the 8 candidates
  if (t == 0){
    unsigned used = 0;
    for (int k = 0; k < 4; k++){
      int best = -1;
      for (int c = 0; c < CAND_; c++){
        if (used & (1u << c)) continue;
        if (best < 0){ best = c; continue; }
        if (csim[c] > csim[best] ||
            (csim[c] == csim[best] && cand[c] < cand[best])) best = c;
      }
      used |= 1u << best;
      order[k] = best;
    }
  }
  __syncthreads();
  // ---- phase E: wave w handles winner k=w
  {
    int c = order[w];
    int e = cand[c];
    const float* xp = teacher + ((size_t)(b*V_ + 1 + 2*(e / P_))*P_ + (e % P_))*D_;
    float ds = 0.f;
#pragma unroll
    for (int j = 0; j < 32; j++)
      ds += xp[lane + 64*j] * rS[lane + 64*j];
    for (int off = 32; off; off >>= 1) ds += __shfl_xor(ds, off, 64);
    if (lane == 0){
      kkw[br*4 + w] = cq[c];
      rkT[br*4 + w] = cdT[c];
      rkS[br*4 + w] = ds;
    }
    const float* src = xp + lane*32;
#pragma unroll
    for (int u = 0; u < 4; u++){
      float4 a  = *(const float4*)(src + u*8);
      float4 b2 = *(const float4*)(src + u*8 + 4);
      int4 pc = { pack2bf(a.x, a.y), pack2bf(a.z, a.w),
                  pack2bf(b2.x, b2.y), pack2bf(b2.z, b2.w) };
      size_t po = ((size_t)(br*5 + w))*D_ + lane*32 + u*8;
      *(int4*)(packT + po) = pc;
      *(int4*)(packS + po) = pc;
    }
  }
}

// -------------------- K3: angle GEMM (R2 config: 128x64, BK=64)
__global__ __launch_bounds__(256) void k_angle_gemm(
    const u16* __restrict__ shT, const u16* __restrict__ shS,
    const u16* __restrict__ packT, const u16* __restrict__ packS,
    float* __restrict__ outT, float* __restrict__ outS){
  __shared__ __align__(16) u16 As[128][72];
  __shared__ __align__(16) u16 Bs[64][72];
  int which = blockIdx.z;
  const u16* A  = which ? shS : shT;
  const u16* Bp = which ? packS : packT;
  float* out = which ? outS : outT;
  int b = blockIdx.y;
  int mt = blockIdx.x % 3, nt = blockIdx.x / 3;
  int m0 = mt*128, n0 = nt*64;
  int t = threadIdx.x, lane = t & 63, w = t >> 6, wm = w >> 1, wn = w & 1;
  f32x4 acc[4][2];
  for (int i = 0; i < 4; i++)
    for (int j = 0; j < 2; j++)
      acc[i][j] = (f32x4){0.f, 0.f, 0.f, 0.f};
  int arow = t >> 1, acol = (t & 1) * 32;
  int brow = t >> 2, bcol = (t & 3) * 16;
  const u16* asrc = A  + ((size_t)(b*384 + m0 + arow))*D_ + acol;
  const u16* bsrc = Bp + ((size_t)(b*640 + n0 + brow))*D_ + bcol;
  int lr = lane & 15;
  for (int k0 = 0; k0 < D_; k0 += 64){
    __syncthreads();
#pragma unroll
    for (int u = 0; u < 4; u++)
      *(int4*)&As[arow][acol + u*8] = *(const int4*)(asrc + k0 + u*8);
    *(int4*)&Bs[brow][bcol]     = *(const int4*)(bsrc + k0);
    *(int4*)&Bs[brow][bcol + 8] = *(const int4*)(bsrc + k0 + 8);
    __syncthreads();
#pragma unroll
    for (int kk = 0; kk < 2; kk++){
      int kof = kk*32 + (lane >> 4) * 8;
      bf16x8 bf0 = *(const bf16x8*)&Bs[wn*32 + lr][kof];
      bf16x8 bf1 = *(const bf16x8*)&Bs[wn*32 + 16 + lr][kof];
#pragma unroll
      for (int mi = 0; mi < 4; mi++){
        bf16x8 af = *(const bf16x8*)&As[wm*64 + mi*16 + lr][kof];
        acc[mi][0] = __builtin_amdgcn_mfma_f32_16x16x32_bf16(af, bf0, acc[mi][0], 0, 0, 0);
        acc[mi][1] = __builtin_amdgcn_mfma_f32_16x16x32_bf16(af, bf1, acc[mi][1], 0, 0, 0);
      }
    }
  }
  int lg = lane >> 4;
#pragma unroll
  for (int mi = 0; mi < 4; mi++)
#pragma unroll
    for (int ni = 0; ni < 2; ni++)
#pragma unroll
      for (int reg = 0; reg < 4; reg++){
        int r_idx = wm*64 + mi*16 + lg*4 + reg;
        int c_idx = wn*32 + ni*16 + lr;
        out[((size_t)(b*384 + m0 + r_idx))*640 + n0 + c_idx] = acc[mi][ni][reg];
      }
}

// ---------- K4: assemble angles + huber + partials (coalesced: r fastest)
__global__ __launch_bounds__(256) void k_assemble(
    const float* __restrict__ outT, const float* __restrict__ outS,
    const float* __restrict__ hhT, const float* __restrict__ hhS,
    const float* __restrict__ rrT, const float* __restrict__ rrS,
    const float* __restrict__ kkw, const float* __restrict__ rkT, const float* __restrict__ rkS,
    double* __restrict__ partials){
  __shared__ double dscr[4];
  int idx = blockIdx.x*256 + threadIdx.x;
  int r = idx & 127, s = (idx >> 7) & 127, bf = idx >> 14;
  int f = bf % 3, b = bf / 3;
  int fs = f*128 + s;
  const float* oT = outT + ((size_t)(b*384 + fs))*640 + r*5;
  const float* oS = outS + ((size_t)(b*384 + fs))*640 + r*5;
  float hh_t = hhT[b*384 + fs], hh_s = hhS[b*384 + fs];
  float rr_tv = rrT[b*128 + r], rr_sv = rrS[b*128 + r];
  float sr_t = oT[4], sr_s = oS[4];
  float nhr_t = sqrtf(fmaxf(hh_t + rr_tv - 2.0f*sr_t, 0.0f));
  float nhr_s = sqrtf(fmaxf(hh_s + rr_sv - 2.0f*sr_s, 0.0f));
  float h1 = 0.f, h2 = 0.f, h3 = 0.f;
#pragma unroll
  for (int k = 0; k < 4; k++){
    float ss_t = oT[k], ss_s = oS[k];
    float kk = kkw[(b*128 + r)*4 + k];
    float rk_t = rkT[(b*128 + r)*4 + k];
    float rk_s = rkS[(b*128 + r)*4 + k];
    float ncr_t = sqrtf(fmaxf(kk + rr_tv - 2.0f*rk_t, 0.0f));
    float ncr_s = sqrtf(fmaxf(kk + rr_sv - 2.0f*rk_s, 0.0f));
    float nhc_t = sqrtf(fmaxf(hh_t + kk - 2.0f*ss_t, 0.0f));
    float nhc_s = sqrtf(fmaxf(hh_s + kk - 2.0f*ss_s, 0.0f));
    float a1t = (ss_t - sr_t - rk_t + rr_tv) / (fmaxf(nhr_t, EPS_) * fmaxf(ncr_t, EPS_));
    float a2t = (sr_t - rk_t - ss_t + kk)    / (fmaxf(ncr_t, EPS_) * fmaxf(nhc_t, EPS_));
    float a3t = (rk_t - sr_t - ss_t + hh_t)  / (fmaxf(nhr_t, EPS_) * fmaxf(nhc_t, EPS_));
    float a1s = (ss_s - sr_s - rk_s + rr_sv) / (fmaxf(nhr_s, EPS_) * fmaxf(ncr_s, EPS_));
    float a2s = (sr_s - rk_s - ss_s + kk)    / (fmaxf(ncr_s, EPS_) * fmaxf(nhc_s, EPS_));
    float a3s = (rk_s - sr_s - ss_s + hh_s)  / (fmaxf(nhr_s, EPS_) * fmaxf(nhc_s, EPS_));
    h1 += huber1(a1s - a1t);
    h2 += huber1(a2s - a2t);
    h3 += huber1(a3s - a3t);
  }
  double d1 = h1, d2 = h2, d3 = h3;
  for (int off = 32; off; off >>= 1){
    d1 += __shfl_xor(d1, off, 64);
    d2 += __shfl_xor(d2, off, 64);
    d3 += __shfl_xor(d3, off, 64);
  }
  int w = threadIdx.x >> 6;
  if ((threadIdx.x & 63) == 0) dscr[w] = d1;
  __syncthreads();
  if (threadIdx.x == 0) partials[blockIdx.x*3 + 0] = dscr[0]+dscr[1]+dscr[2]+dscr[3];
  __syncthreads();
  if ((threadIdx.x & 63) == 0) dscr[w] = d2;
  __syncthreads();
  if (threadIdx.x == 0) partials[blockIdx.x*3 + 1] = dscr[0]+dscr[1]+dscr[2]+dscr[3];
  __syncthreads();
  if ((threadIdx.x & 63) == 0) dscr[w] = d3;
  __syncthreads();
  if (threadIdx.x == 0) partials[blockIdx.x*3 + 2] = dscr[0]+dscr[1]+dscr[2]+dscr[3];
}

// ------------------------------------------------------------- K5: final reduce
__global__ __launch_bounds__(256) void k_final(
    const double* __restrict__ partials, float* __restrict__ out){
  __shared__ double dscr[12];
  int t = threadIdx.x;
  double l1 = 0, l2 = 0, l3 = 0;
  for (int i = t; i < 768; i += 256){
    l1 += partials[i*3 + 0];
    l2 += partials[i*3 + 1];
    l3 += partials[i*3 + 2];
  }
  for (int off = 32; off; off >>= 1){
    l1 += __shfl_xor(l1, off, 64);
    l2 += __shfl_xor(l2, off, 64);
    l3 += __shfl_xor(l3, off, 64);
  }
  int w = t >> 6;
  if ((t & 63) == 0){ dscr[w*3] = l1; dscr[w*3+1] = l2; dscr[w*3+2] = l3; }
  __syncthreads();
  if (t == 0){
    double L1 = dscr[0] + dscr[3] + dscr[6] + dscr[9];
    double L2 = dscr[1] + dscr[4] + dscr[7] + dscr[10];
    double L3 = dscr[2] + dscr[5] + dscr[8] + dscr[11];
    out[0] = (float)((L1 + L2 + L3) / 786432.0);
  }
}

extern "C" void kernel_launch(void* const* d_in, const int* in_sizes, int n_in,
                              void* d_out, int out_size, void* d_ws, size_t ws_size,
                              hipStream_t stream){
  (void)in_sizes; (void)n_in; (void)out_size; (void)ws_size;
  const float* teacher = (const float*)d_in[0];
  const float* student = (const float*)d_in[1];
  const int* ref_perm = (const int*)d_in[2];
  const int* shared_perm = (const int*)d_in[3];
  float* out = (float*)d_out;

  char* ws = (char*)d_ws;
  size_t off = 0;
  auto alloc = [&](size_t bytes)->char*{
    char* pp = ws + off;
    off += (bytes + 255) & ~(size_t)255;
    return pp;
  };
  u16*    ref_tn  = (u16*)   alloc((size_t)B_*R_*D_*sizeof(u16));        // 2 MB
  float*  rr_t    = (float*) alloc(B_*R_*sizeof(float));
  float*  rr_s    = (float*) alloc(B_*R_*sizeof(float));
  float*  kkw     = (float*) alloc(B_*R_*K_*sizeof(float));
  float*  rkT     = (float*) alloc(B_*R_*K_*sizeof(float));
  float*  rkS     = (float*) alloc(B_*R_*K_*sizeof(float));
  u16*    shT     = (u16*)   alloc((size_t)B_*384*D_*sizeof(u16));       // 6.3 MB
  u16*    shS     = (u16*)   alloc((size_t)B_*384*D_*sizeof(u16));       // 6.3 MB
  float*  hhT     = (float*) alloc(B_*384*sizeof(float));
  float*  hhS     = (float*) alloc(B_*384*sizeof(float));
  float*  outT    = (float*) alloc((size_t)B_*384*640*sizeof(float));    // 3.9 MB
  float*  outS    = (float*) alloc((size_t)B_*384*640*sizeof(float));    // 3.9 MB
  double* partials= (double*)alloc(768*3*sizeof(double));
  float*  simPart = (float*) alloc((size_t)2*B_*R_*E_*sizeof(float));    // 22.4 MB
  float*  nsqPart = (float*) alloc((size_t)2*B_*E_*sizeof(float));       // 175 KB
  u16*    packT   = (u16*)   alloc((size_t)B_*R_*5*D_*sizeof(u16));      // 10.5 MB
  u16*    packS   = (u16*)   alloc((size_t)B_*R_*5*D_*sizeof(u16));      // 10.5 MB

  k_prep_ref<<<dim3(B_*R_), dim3(256), 0, stream>>>(teacher, student, ref_perm,
                                                    ref_tn, rr_t, rr_s);
  k_sim_fused<<<dim3(SIMBLK_ + 1536), dim3(256), 0, stream>>>(
      teacher, student, ref_tn, shared_perm, simPart, nsqPart, shT, shS, hhT, hhS);
  k_rescore<<<dim3(B_*R_), dim3(256), 0, stream>>>(teacher, student, ref_perm,
                                                   simPart, nsqPart, rr_t,
                                                   packT, packS, kkw, rkT, rkS);
  k_angle_gemm<<<dim3(30, B_, 2), dim3(256), 0, stream>>>(shT, shS, packT, packS, outT, outS);
  k_assemble<<<dim3(768), dim3(256), 0, stream>>>(outT, outS, hhT, hhS, rr_t, rr_s, kkw, rkT, rkS, partials);
  k_final<<<dim3(1), dim3(256), 0, stream>>>(partials, out);
}

// Round 5
// 126.355 us; speedup vs baseline: 1.2676x; 1.0590x over previous
//
#include <hip/hip_runtime.h>
#include <hip/hip_bf16.h>

#define B_ 4
#define V_ 8
#define P_ 1369
#define D_ 2048
#define R_ 128
#define F_ 3
#define K_ 4
#define E_ 5476          // 4*P_
#define CAND_ 8
#define EPS_ 1e-8f
#define ETILES_ 86       // ceil(E_/64)
#define SIMBLK_ (ETILES_*B_*2)   // 688 split-K sim blocks
#define HOFF_ ((size_t)B_*384*640)

typedef unsigned short u16;
typedef __attribute__((ext_vector_type(8))) short bf16x8;
typedef __attribute__((ext_vector_type(4))) float f32x4;

// v_cvt_pk_bf16_f32 via compiler (RNE, same bits as manual round-to-nearest-even)
__device__ inline int pack2bf(float lo, float hi){
  __hip_bfloat162 h = __float22bfloat162_rn(make_float2(lo, hi));
  int r; __builtin_memcpy(&r, &h, 4); return r;
}
__device__ inline float sq8(float4 a, float4 b){
  return a.x*a.x + a.y*a.y + a.z*a.z + a.w*a.w
       + b.x*b.x + b.y*b.y + b.z*b.z + b.w*b.w;
}
__device__ inline float huber1(float e){
  float ae = fabsf(e);
  return ae <= 1.0f ? 0.5f*e*e : (ae - 0.5f);
}
__device__ inline float blk_sum(float v, float* scr){
  for (int off = 32; off; off >>= 1) v += __shfl_xor(v, off, 64);
  __syncthreads();
  if ((threadIdx.x & 63) == 0) scr[threadIdx.x >> 6] = v;
  __syncthreads();
  float s = scr[0] + scr[1] + scr[2] + scr[3];
  __syncthreads();
  return s;
}

// -------------------------------------------------- K0: ref-row prep (512 blocks)
__global__ __launch_bounds__(256) void k_prep_ref(
    const float* __restrict__ teacher, const float* __restrict__ student,
    const int* __restrict__ ref_perm,
    u16* __restrict__ ref_tn, float* __restrict__ rr_t, float* __restrict__ rr_s){
  __shared__ float scr[4];
  int br = blockIdx.x, b = br >> 7, r = br & 127, t = threadIdx.x;
  int p = ref_perm[r];
  const float* tp = teacher + ((size_t)(b*V_)*P_ + p)*D_;
  const float* sp = student + ((size_t)(b*4)*P_ + p)*D_;
  float4 x0 = *(const float4*)(tp + t*8);
  float4 x1 = *(const float4*)(tp + t*8 + 4);
  float sumt = blk_sum(sq8(x0, x1), scr);
  float4 y0 = *(const float4*)(sp + t*8);
  float4 y1 = *(const float4*)(sp + t*8 + 4);
  float sums = blk_sum(sq8(y0, y1), scr);
  if (t == 0){ rr_t[br] = sumt; rr_s[br] = sums; }
  float inv = 1.0f / fmaxf(sqrtf(sumt), 1e-12f);
  int4 pt = { pack2bf(x0.x*inv, x0.y*inv), pack2bf(x0.z*inv, x0.w*inv),
              pack2bf(x1.x*inv, x1.y*inv), pack2bf(x1.z*inv, x1.w*inv) };
  *(int4*)(ref_tn + (size_t)br*D_ + t*8) = pt;
}

// ---- K1: FUSED dispatch: [0,688) split-K sim GEMM blocks; [688,2224) shared-prep
// sim: tile 128x64, BK=64, K-half per block; pipelined loads; fp32 partial C+norms
__global__ __launch_bounds__(256) void k_sim_fused(
    const float* __restrict__ teacher, const float* __restrict__ student,
    const u16* __restrict__ ref_tn, const int* __restrict__ shared_perm,
    float* __restrict__ simPart, float* __restrict__ nsqPart,
    u16* __restrict__ shT, u16* __restrict__ shS,
    float* __restrict__ hhT, float* __restrict__ hhS){
  __shared__ __align__(16) u16 As[128][72];
  __shared__ __align__(16) u16 Bs[64][72];
  __shared__ float scr4[4];
  int bx = blockIdx.x, t = threadIdx.x;
  if (bx < SIMBLK_){
    int h = bx / (ETILES_*B_);
    int rem = bx % (ETILES_*B_);
    int b = rem / ETILES_, et = rem % ETILES_;
    int e0 = et * 64;
    int lane = t & 63, w = t >> 6, wm = w >> 1, wn = w & 1;
    f32x4 acc[4][2];
    for (int i = 0; i < 4; i++)
      for (int j = 0; j < 2; j++)
        acc[i][j] = (f32x4){0.f, 0.f, 0.f, 0.f};
    int arow = t >> 1, acol = (t & 1) * 32;
    int brow = t >> 2, bcol = (t & 3) * 16;
    int e = e0 + brow;
    const u16* asrc = ref_tn + ((size_t)(b*128 + arow))*D_ + acol;
    const float* bsrc = nullptr;
    if (e < E_) bsrc = teacher + ((size_t)(b*V_ + 1 + 2*(e / P_))*P_ + (e % P_))*D_ + bcol;
    float q = 0.0f;
    int lr = lane & 15;
    int kbeg = h * 1024, kend = kbeg + 1024;
    int4 aa0, aa1, aa2, aa3;
    float4 za0, za1, za2, za3;
    // prologue load
    {
      aa0 = *(const int4*)(asrc + kbeg);      aa1 = *(const int4*)(asrc + kbeg + 8);
      aa2 = *(const int4*)(asrc + kbeg + 16); aa3 = *(const int4*)(asrc + kbeg + 24);
      if (bsrc){
        za0 = *(const float4*)(bsrc + kbeg);      za1 = *(const float4*)(bsrc + kbeg + 4);
        za2 = *(const float4*)(bsrc + kbeg + 8);  za3 = *(const float4*)(bsrc + kbeg + 12);
      } else { za0 = make_float4(0.f,0.f,0.f,0.f); za1 = za0; za2 = za0; za3 = za0; }
    }
    for (int k0 = kbeg; k0 < kend; k0 += 64){
      __syncthreads();
      *(int4*)&As[arow][acol]      = aa0;
      *(int4*)&As[arow][acol + 8]  = aa1;
      *(int4*)&As[arow][acol + 16] = aa2;
      *(int4*)&As[arow][acol + 24] = aa3;
      q += sq8(za0, za1) + sq8(za2, za3);
      int4 p0 = { pack2bf(za0.x, za0.y), pack2bf(za0.z, za0.w),
                  pack2bf(za1.x, za1.y), pack2bf(za1.z, za1.w) };
      int4 p1 = { pack2bf(za2.x, za2.y), pack2bf(za2.z, za2.w),
                  pack2bf(za3.x, za3.y), pack2bf(za3.z, za3.w) };
      *(int4*)&Bs[brow][bcol]     = p0;
      *(int4*)&Bs[brow][bcol + 8] = p1;
      __syncthreads();
      int kn = k0 + 64;
      if (kn < kend){   // issue next-tile loads BEFORE the MFMA cluster
        aa0 = *(const int4*)(asrc + kn);      aa1 = *(const int4*)(asrc + kn + 8);
        aa2 = *(const int4*)(asrc + kn + 16); aa3 = *(const int4*)(asrc + kn + 24);
        if (bsrc){
          za0 = *(const float4*)(bsrc + kn);      za1 = *(const float4*)(bsrc + kn + 4);
          za2 = *(const float4*)(bsrc + kn + 8);  za3 = *(const float4*)(bsrc + kn + 12);
        }
      }
#pragma unroll
      for (int kk = 0; kk < 2; kk++){
        int kof = kk*32 + (lane >> 4) * 8;
        bf16x8 bf0 = *(const bf16x8*)&Bs[wn*32 + lr][kof];
        bf16x8 bf1 = *(const bf16x8*)&Bs[wn*32 + 16 + lr][kof];
#pragma unroll
        for (int mi = 0; mi < 4; mi++){
          bf16x8 af = *(const bf16x8*)&As[wm*64 + mi*16 + lr][kof];
          acc[mi][0] = __builtin_amdgcn_mfma_f32_16x16x32_bf16(af, bf0, acc[mi][0], 0, 0, 0);
          acc[mi][1] = __builtin_amdgcn_mfma_f32_16x16x32_bf16(af, bf1, acc[mi][1], 0, 0, 0);
        }
      }
    }
    // partial row-norms: 4 threads per e-row
    q += __shfl_xor(q, 1, 64);
    q += __shfl_xor(q, 2, 64);
    if ((t & 3) == 0 && e < E_) nsqPart[(size_t)(h*4 + b)*E_ + e] = q;
    int lg = lane >> 4;
#pragma unroll
    for (int mi = 0; mi < 4; mi++){
#pragma unroll
      for (int ni = 0; ni < 2; ni++){
        int el = wn*32 + ni*16 + lr;
        int e_idx = e0 + el;
        if (e_idx < E_){
#pragma unroll
          for (int reg = 0; reg < 4; reg++){
            int r_idx = wm*64 + mi*16 + lg*4 + reg;
            simPart[((size_t)((h*4 + b)*128 + r_idx))*E_ + e_idx] = acc[mi][ni][reg];
          }
        }
      }
    }
  } else {
    // ---------------- shared-row prep (1536 blocks)
    int id = bx - SIMBLK_;
    int b = id / 384, fs = id % 384;
    int f = fs >> 7, s = fs & 127;
    int p = shared_perm[s];
    const float* tp = teacher + ((size_t)(b*V_ + 2 + 2*f)*P_ + p)*D_;
    const float* sp = student + ((size_t)(b*4 + 1 + f)*P_ + p)*D_;
    float4 x0 = *(const float4*)(tp + t*8);
    float4 x1 = *(const float4*)(tp + t*8 + 4);
    float sumt = blk_sum(sq8(x0, x1), scr4);
    int4 pt = { pack2bf(x0.x, x0.y), pack2bf(x0.z, x0.w),
                pack2bf(x1.x, x1.y), pack2bf(x1.z, x1.w) };
    *(int4*)(shT + (size_t)id*D_ + t*8) = pt;
    float4 y0 = *(const float4*)(sp + t*8);
    float4 y1 = *(const float4*)(sp + t*8 + 4);
    float sums = blk_sum(sq8(y0, y1), scr4);
    int4 ps = { pack2bf(y0.x, y0.y), pack2bf(y0.z, y0.w),
                pack2bf(y1.x, y1.y), pack2bf(y1.z, y1.w) };
    *(int4*)(shS + (size_t)id*D_ + t*8) = ps;
    if (t == 0){ hhT[id] = sumt; hhS[id] = sums; }
  }
}

// ---- K2: combine partials + top-8 select + fp32 rescore + exact top-4 + pack
__global__ __launch_bounds__(256) void k_rescore(
    const float* __restrict__ teacher, const float* __restrict__ student,
    const int* __restrict__ ref_perm,
    const float* __restrict__ simPart, const float* __restrict__ nsqPart,
    const float* __restrict__ rr_t,
    u16* __restrict__ packT, u16* __restrict__ packS,
    float* __restrict__ kkw, float* __restrict__ rkT, float* __restrict__ rkS){
  __shared__ float v[E_];
  __shared__ float rT[D_];
  __shared__ float rS[D_];
  __shared__ float tv[256];
  __shared__ int   ti[256];
  __shared__ float rv[4];
  __shared__ int ri[4];
  __shared__ int cand[CAND_];
  __shared__ float csim[CAND_], cq[CAND_], cdT[CAND_];
  __shared__ int order[4];
  int br = blockIdx.x, b = br >> 7, r = br & 127, t = threadIdx.x;
  int lane = t & 63, w = t >> 6;
  // ---- phase A: combine split-K partials -> normalized sim row; top-8
  const float* p0 = simPart + ((size_t)(b*128 + r))*E_;
  const float* p1 = simPart + ((size_t)((4 + b)*128 + r))*E_;
  const float* q0 = nsqPart + (size_t)b*E_;
  const float* q1 = nsqPart + (size_t)(4 + b)*E_;
  for (int i = t; i < E_; i += 256){
    float qq = q0[i] + q1[i];
    float inv = 1.0f / fmaxf(sqrtf(qq), 1e-12f);
    v[i] = (p0[i] + p1[i]) * inv;
  }
  __syncthreads();
  {
    float bv = -3.4e38f; int bi = 0x7fffffff;
    for (int i = t; i < E_; i += 256){
      float x = v[i];
      if (x > bv){ bv = x; bi = i; }
    }
    tv[t] = bv; ti[t] = bi;
  }
  __syncthreads();
  for (int c = 0; c < CAND_; c++){
    float mv = tv[t]; int mi2 = ti[t];
    for (int off = 32; off; off >>= 1){
      float ov = __shfl_down(mv, off, 64);
      int   oi = __shfl_down(mi2, off, 64);
      if (ov > mv || (ov == mv && oi < mi2)){ mv = ov; mi2 = oi; }
    }
    if (lane == 0){ rv[w] = mv; ri[w] = mi2; }
    __syncthreads();
    if (t == 0){
      for (int w2 = 1; w2 < 4; w2++)
        if (rv[w2] > rv[0] || (rv[w2] == rv[0] && ri[w2] < ri[0])){ rv[0] = rv[w2]; ri[0] = ri[w2]; }
      cand[c] = ri[0];
      v[ri[0]] = -3.4e38f;
    }
    __syncthreads();
    int win = cand[c];
    if (t == (win & 255)){
      float nb = -3.4e38f; int nbi = 0x7fffffff;
      for (int i = t; i < E_; i += 256){
        float x = v[i];
        if (x > nb){ nb = x; nbi = i; }
      }
      tv[t] = nb; ti[t] = nbi;
    }
    __syncthreads();
  }
  // ---- phase B: ref rows to LDS + pack j=4
  int p = ref_perm[r];
  const float* tp = teacher + ((size_t)(b*V_)*P_ + p)*D_;
  const float* sp = student + ((size_t)(b*4)*P_ + p)*D_;
  float4 x0 = *(const float4*)(tp + t*8);
  float4 x1 = *(const float4*)(tp + t*8 + 4);
  float4 y0 = *(const float4*)(sp + t*8);
  float4 y1 = *(const float4*)(sp + t*8 + 4);
  *(float4*)&rT[t*8]   = x0; *(float4*)&rT[t*8+4] = x1;
  *(float4*)&rS[t*8]   = y0; *(float4*)&rS[t*8+4] = y1;
  {
    int4 pt = { pack2bf(x0.x, x0.y), pack2bf(x0.z, x0.w),
                pack2bf(x1.x, x1.y), pack2bf(x1.z, x1.w) };
    *(int4*)(packT + ((size_t)(br*5 + 4))*D_ + t*8) = pt;
    int4 ps = { pack2bf(y0.x, y0.y), pack2bf(y0.z, y0.w),
                pack2bf(y1.x, y1.y), pack2bf(y1.z, y1.w) };
    *(int4*)(packS + ((size_t)(br*5 + 4))*D_ + t*8) = ps;
  }
  float invt = 1.0f / fmaxf(sqrtf(rr_t[br]), 1e-12f);
  __syncthreads();
  // ---- phase C: wave-parallel candidate scoring
  for (int c = w; c < CAND_; c += 4){
    int e = cand[c];
    const float* xp = teacher + ((size_t)(b*V_ + 1 + 2*(e / P_))*P_ + (e % P_))*D_;
    float d = 0.f, q = 0.f;
#pragma unroll
    for (int j = 0; j < 32; j++){
      float xv = xp[lane + 64*j];
      d += xv * rT[lane + 64*j];
      q += xv * xv;
    }
    for (int off = 32; off; off >>= 1){
      d += __shfl_xor(d, off, 64);
      q += __shfl_xor(q, off, 64);
    }
    if (lane == 0){
      cdT[c] = d; cq[c] = q;
      csim[c] = d * invt / fmaxf(sqrtf(q), 1e-12f);
    }
  }
  __syncthreads();
  // ---- phase D: exact top-4 among the 8 candidates
  if (t == 0){
    unsigned used = 0;
    for (int k = 0; k < 4; k++){
      int best = -1;
      for (int c = 0; c < CAND_; c++){
        if (used & (1u << c)) continue;
        if (best < 0){ best = c; continue; }
        if (csim[c] > csim[best] ||
            (csim[c] == csim[best] && cand[c] < cand[best])) best = c;
      }
      used |= 1u << best;
      order[k] = best;
    }
  }
  __syncthreads();
  // ---- phase E: wave w handles winner k=w
  {
    int c = order[w];
    int e = cand[c];
    const float* xp = teacher + ((size_t)(b*V_ + 1 + 2*(e / P_))*P_ + (e % P_))*D_;
    float ds = 0.f;
#pragma unroll
    for (int j = 0; j < 32; j++)
      ds += xp[lane + 64*j] * rS[lane + 64*j];
    for (int off = 32; off; off >>= 1) ds += __shfl_xor(ds, off, 64);
    if (lane == 0){
      kkw[br*4 + w] = cq[c];
      rkT[br*4 + w] = cdT[c];
      rkS[br*4 + w] = ds;
    }
    const float* src = xp + lane*32;
#pragma unroll
    for (int u = 0; u < 4; u++){
      float4 a  = *(const float4*)(src + u*8);
      float4 b2 = *(const float4*)(src + u*8 + 4);
      int4 pc = { pack2bf(a.x, a.y), pack2bf(a.z, a.w),
                  pack2bf(b2.x, b2.y), pack2bf(b2.z, b2.w) };
      size_t po = ((size_t)(br*5 + w))*D_ + lane*32 + u*8;
      *(int4*)(packT + po) = pc;
      *(int4*)(packS + po) = pc;
    }
  }
}

// ------- K3: angle GEMM, 128x64, BK=64, split-K x2, pipelined register loads
__global__ __launch_bounds__(256) void k_angle_gemm(
    const u16* __restrict__ shT, const u16* __restrict__ shS,
    const u16* __restrict__ packT, const u16* __restrict__ packS,
    float* __restrict__ outT, float* __restrict__ outS){
  __shared__ __align__(16) u16 As[128][72];
  __shared__ __align__(16) u16 Bs[64][72];
  int which = blockIdx.z >> 1, h = blockIdx.z & 1;
  const u16* A  = which ? shS : shT;
  const u16* Bp = which ? packS : packT;
  float* out = (which ? outS : outT) + h * HOFF_;
  int b = blockIdx.y;
  int mt = blockIdx.x % 3, nt = blockIdx.x / 3;
  int m0 = mt*128, n0 = nt*64;
  int t = threadIdx.x, lane = t & 63, w = t >> 6, wm = w >> 1, wn = w & 1;
  f32x4 acc[4][2];
  for (int i = 0; i < 4; i++)
    for (int j = 0; j < 2; j++)
      acc[i][j] = (f32x4){0.f, 0.f, 0.f, 0.f};
  int arow = t >> 1, acol = (t & 1) * 32;
  int brow = t >> 2, bcol = (t & 3) * 16;
  const u16* asrc = A  + ((size_t)(b*384 + m0 + arow))*D_ + acol;
  const u16* bsrc = Bp + ((size_t)(b*640 + n0 + brow))*D_ + bcol;
  int lr = lane & 15;
  int kbeg = h * 1024, kend = kbeg + 1024;
  int4 ra0, ra1, ra2, ra3, rb0, rb1;
  ra0 = *(const int4*)(asrc + kbeg);      ra1 = *(const int4*)(asrc + kbeg + 8);
  ra2 = *(const int4*)(asrc + kbeg + 16); ra3 = *(const int4*)(asrc + kbeg + 24);
  rb0 = *(const int4*)(bsrc + kbeg);      rb1 = *(const int4*)(bsrc + kbeg + 8);
  for (int k0 = kbeg; k0 < kend; k0 += 64){
    __syncthreads();
    *(int4*)&As[arow][acol]      = ra0;
    *(int4*)&As[arow][acol + 8]  = ra1;
    *(int4*)&As[arow][acol + 16] = ra2;
    *(int4*)&As[arow][acol + 24] = ra3;
    *(int4*)&Bs[brow][bcol]     = rb0;
    *(int4*)&Bs[brow][bcol + 8] = rb1;
    __syncthreads();
    int kn = k0 + 64;
    if (kn < kend){
      ra0 = *(const int4*)(asrc + kn);      ra1 = *(const int4*)(asrc + kn + 8);
      ra2 = *(const int4*)(asrc + kn + 16); ra3 = *(const int4*)(asrc + kn + 24);
      rb0 = *(const int4*)(bsrc + kn);      rb1 = *(const int4*)(bsrc + kn + 8);
    }
#pragma unroll
    for (int kk = 0; kk < 2; kk++){
      int kof = kk*32 + (lane >> 4) * 8;
      bf16x8 bf0 = *(const bf16x8*)&Bs[wn*32 + lr][kof];
      bf16x8 bf1 = *(const bf16x8*)&Bs[wn*32 + 16 + lr][kof];
#pragma unroll
      for (int mi = 0; mi < 4; mi++){
        bf16x8 af = *(const bf16x8*)&As[wm*64 + mi*16 + lr][kof];
        acc[mi][0] = __builtin_amdgcn_mfma_f32_16x16x32_bf16(af, bf0, acc[mi][0], 0, 0, 0);
        acc[mi][1] = __builtin_amdgcn_mfma_f32_16x16x32_bf16(af, bf1, acc[mi][1], 0, 0, 0);
      }
    }
  }
  int lg = lane >> 4;
#pragma unroll
  for (int mi = 0; mi < 4; mi++)
#pragma unroll
    for (int ni = 0; ni < 2; ni++)
#pragma unroll
      for (int reg = 0; reg < 4; reg++){
        int r_idx = wm*64 + mi*16 + lg*4 + reg;
        int c_idx = wn*32 + ni*16 + lr;
        out[((size_t)(b*384 + m0 + r_idx))*640 + n0 + c_idx] = acc[mi][ni][reg];
      }
}

// ---------- K4: assemble angles + huber + partials (sums split-K halves)
__global__ __launch_bounds__(256) void k_assemble(
    const float* __restrict__ outT, const float* __restrict__ outS,
    const float* __restrict__ hhT, const float* __restrict__ hhS,
    const float* __restrict__ rrT, const float* __restrict__ rrS,
    const float* __restrict__ kkw, const float* __restrict__ rkT, const float* __restrict__ rkS,
    double* __restrict__ partials){
  __shared__ double dscr[4];
  int idx = blockIdx.x*256 + threadIdx.x;
  int r = idx & 127, s = (idx >> 7) & 127, bf = idx >> 14;
  int f = bf % 3, b = bf / 3;
  int fs = f*128 + s;
  size_t base = ((size_t)(b*384 + fs))*640 + r*5;
  const float* oT0 = outT + base; const float* oT1 = oT0 + HOFF_;
  const float* oS0 = outS + base; const float* oS1 = oS0 + HOFF_;
  float hh_t = hhT[b*384 + fs], hh_s = hhS[b*384 + fs];
  float rr_tv = rrT[b*128 + r], rr_sv = rrS[b*128 + r];
  float sr_t = oT0[4] + oT1[4], sr_s = oS0[4] + oS1[4];
  float nhr_t = sqrtf(fmaxf(hh_t + rr_tv - 2.0f*sr_t, 0.0f));
  float nhr_s = sqrtf(fmaxf(hh_s + rr_sv - 2.0f*sr_s, 0.0f));
  float h1 = 0.f, h2 = 0.f, h3 = 0.f;
#pragma unroll
  for (int k = 0; k < 4; k++){
    float ss_t = oT0[k] + oT1[k], ss_s = oS0[k] + oS1[k];
    float kk = kkw[(b*128 + r)*4 + k];
    float rk_t = rkT[(b*128 + r)*4 + k];
    float rk_s = rkS[(b*128 + r)*4 + k];
    float ncr_t = sqrtf(fmaxf(kk + rr_tv - 2.0f*rk_t, 0.0f));
    float ncr_s = sqrtf(fmaxf(kk + rr_sv - 2.0f*rk_s, 0.0f));
    float nhc_t = sqrtf(fmaxf(hh_t + kk - 2.0f*ss_t, 0.0f));
    float nhc_s = sqrtf(fmaxf(hh_s + kk - 2.0f*ss_s, 0.0f));
    float a1t = (ss_t - sr_t - rk_t + rr_tv) / (fmaxf(nhr_t, EPS_) * fmaxf(ncr_t, EPS_));
    float a2t = (sr_t - rk_t - ss_t + kk)    / (fmaxf(ncr_t, EPS_) * fmaxf(nhc_t, EPS_));
    float a3t = (rk_t - sr_t - ss_t + hh_t)  / (fmaxf(nhr_t, EPS_) * fmaxf(nhc_t, EPS_));
    float a1s = (ss_s - sr_s - rk_s + rr_sv) / (fmaxf(nhr_s, EPS_) * fmaxf(ncr_s, EPS_));
    float a2s = (sr_s - rk_s - ss_s + kk)    / (fmaxf(ncr_s, EPS_) * fmaxf(nhc_s, EPS_));
    float a3s = (rk_s - sr_s - ss_s + hh_s)  / (fmaxf(nhr_s, EPS_) * fmaxf(nhc_s, EPS_));
    h1 += huber1(a1s - a1t);
    h2 += huber1(a2s - a2t);
    h3 += huber1(a3s - a3t);
  }
  double d1 = h1, d2 = h2, d3 = h3;
  for (int off = 32; off; off >>= 1){
    d1 += __shfl_xor(d1, off, 64);
    d2 += __shfl_xor(d2, off, 64);
    d3 += __shfl_xor(d3, off, 64);
  }
  int w = threadIdx.x >> 6;
  if ((threadIdx.x & 63) == 0) dscr[w] = d1;
  __syncthreads();
  if (threadIdx.x == 0) partials[blockIdx.x*3 + 0] = dscr[0]+dscr[1]+dscr[2]+dscr[3];
  __syncthreads();
  if ((threadIdx.x & 63) == 0) dscr[w] = d2;
  __syncthreads();
  if (threadIdx.x == 0) partials[blockIdx.x*3 + 1] = dscr[0]+dscr[1]+dscr[2]+dscr[3];
  __syncthreads();
  if ((threadIdx.x & 63) == 0) dscr[w] = d3;
  __syncthreads();
  if (threadIdx.x == 0) partials[blockIdx.x*3 + 2] = dscr[0]+dscr[1]+dscr[2]+dscr[3];
}

// ------------------------------------------------------------- K5: final reduce
__global__ __launch_bounds__(256) void k_final(
    const double* __restrict__ partials, float* __restrict__ out){
  __shared__ double dscr[12];
  int t = threadIdx.x;
  double l1 = 0, l2 = 0, l3 = 0;
  for (int i = t; i < 768; i += 256){
    l1 += partials[i*3 + 0];
    l2 += partials[i*3 + 1];
    l3 += partials[i*3 + 2];
  }
  for (int off = 32; off; off >>= 1){
    l1 += __shfl_xor(l1, off, 64);
    l2 += __shfl_xor(l2, off, 64);
    l3 += __shfl_xor(l3, off, 64);
  }
  int w = t >> 6;
  if ((t & 63) == 0){ dscr[w*3] = l1; dscr[w*3+1] = l2; dscr[w*3+2] = l3; }
  __syncthreads();
  if (t == 0){
    double L1 = dscr[0] + dscr[3] + dscr[6] + dscr[9];
    double L2 = dscr[1] + dscr[4] + dscr[7] + dscr[10];
    double L3 = dscr[2] + dscr[5] + dscr[8] + dscr[11];
    out[0] = (float)((L1 + L2 + L3) / 786432.0);
  }
}

extern "C" void kernel_launch(void* const* d_in, const int* in_sizes, int n_in,
                              void* d_out, int out_size, void* d_ws, size_t ws_size,
                              hipStream_t stream){
  (void)in_sizes; (void)n_in; (void)out_size; (void)ws_size;
  const float* teacher = (const float*)d_in[0];
  const float* student = (const float*)d_in[1];
  const int* ref_perm = (const int*)d_in[2];
  const int* shared_perm = (const int*)d_in[3];
  float* out = (float*)d_out;

  char* ws = (char*)d_ws;
  size_t off = 0;
  auto alloc = [&](size_t bytes)->char*{
    char* pp = ws + off;
    off += (bytes + 255) & ~(size_t)255;
    return pp;
  };
  u16*    ref_tn  = (u16*)   alloc((size_t)B_*R_*D_*sizeof(u16));        // 2 MB
  float*  rr_t    = (float*) alloc(B_*R_*sizeof(float));
  float*  rr_s    = (float*) alloc(B_*R_*sizeof(float));
  float*  kkw     = (float*) alloc(B_*R_*K_*sizeof(float));
  float*  rkT     = (float*) alloc(B_*R_*K_*sizeof(float));
  float*  rkS     = (float*) alloc(B_*R_*K_*sizeof(float));
  u16*    shT     = (u16*)   alloc((size_t)B_*384*D_*sizeof(u16));       // 6.3 MB
  u16*    shS     = (u16*)   alloc((size_t)B_*384*D_*sizeof(u16));       // 6.3 MB
  float*  hhT     = (float*) alloc(B_*384*sizeof(float));
  float*  hhS     = (float*) alloc(B_*384*sizeof(float));
  float*  outT    = (float*) alloc((size_t)2*B_*384*640*sizeof(float));  // 7.9 MB
  float*  outS    = (float*) alloc((size_t)2*B_*384*640*sizeof(float));  // 7.9 MB
  double* partials= (double*)alloc(768*3*sizeof(double));
  float*  simPart = (float*) alloc((size_t)2*B_*R_*E_*sizeof(float));    // 22.4 MB
  float*  nsqPart = (float*) alloc((size_t)2*B_*E_*sizeof(float));       // 175 KB
  u16*    packT   = (u16*)   alloc((size_t)B_*R_*5*D_*sizeof(u16));      // 10.5 MB
  u16*    packS   = (u16*)   alloc((size_t)B_*R_*5*D_*sizeof(u16));      // 10.5 MB

  k_prep_ref<<<dim3(B_*R_), dim3(256), 0, stream>>>(teacher, student, ref_perm,
                                                    ref_tn, rr_t, rr_s);
  k_sim_fused<<<dim3(SIMBLK_ + 1536), dim3(256), 0, stream>>>(
      teacher, student, ref_tn, shared_perm, simPart, nsqPart, shT, shS, hhT, hhS);
  k_rescore<<<dim3(B_*R_), dim3(256), 0, stream>>>(teacher, student, ref_perm,
                                                   simPart, nsqPart, rr_t,
                                                   packT, packS, kkw, rkT, rkS);
  k_angle_gemm<<<dim3(30, B_, 4), dim3(256), 0, stream>>>(shT, shS, packT, packS, outT, outS);
  k_assemble<<<dim3(768), dim3(256), 0, stream>>>(outT, outS, hhT, hhS, rr_t, rr_s, kkw, rkT, rkS, partials);
  k_final<<<dim3(1), dim3(256), 0, stream>>>(partials, out);
}